// Round 5
// baseline (551.907 us; speedup 1.0000x reference)
//
#include <hip/hip_runtime.h>
#include <hip/hip_bf16.h>
#include <float.h>

#define NB 32
#define NBCE 32
#define L 128
#define NT 1024
#define R 132                      /* row stride of mirror-square */
#define PAD 40
#define MAXD 8                     /* max tile-diagonals (L/16) */
#define LOGMIN -87.49823f          /* ln(1e-38) */

// ---- mask dtype runtime detection (element [0] is guaranteed true: lens >= 64) ----
__device__ __forceinline__ int mask_mode(const void* p) {
    unsigned int v = ((const unsigned int*)p)[0];
    if (v == 1u) return 1;
    if (v == 0x3F800000u) return 2;
    return 0;
}
__device__ __forceinline__ bool mask_at(const void* p, int mode, int idx) {
    if (mode == 1) return ((const int*)p)[idx] != 0;
    if (mode == 2) return ((const float*)p)[idx] != 0.0f;
    return ((const unsigned char*)p)[idx] != 0;
}

__device__ __forceinline__ float lse2(float a, float b) {
    return fmaxf(a, b) + log1pf(__expf(-fabsf(a - b)));
}

// online-LSE accumulate / merge
__device__ __forceinline__ void lse_acc(float v, float& m, float& s) {
    float nm = fmaxf(m, v);
    s = s * __expf(m - nm) + __expf(v - nm);
    m = nm;
}
__device__ __forceinline__ void lse_merge(float& m1, float& s1, float m2, float s2) {
    float M = fmaxf(m1, m2);
    s1 = s1 * __expf(m1 - M) + s2 * __expf(m2 - M);
    m1 = M;
}

// ---- DPP helpers ----
template<int C>
__device__ __forceinline__ float dppf(float x) {
    return __int_as_float(__builtin_amdgcn_mov_dpp(__float_as_int(x), C, 0xF, 0xF, true));
}
// butterfly LSE-merge over aligned 4-lane groups (lane^1, lane^2)
__device__ __forceinline__ void bfly4_lse(float& m, float& s) {
    float mo = dppf<0xB1>(m), so = dppf<0xB1>(s);
    lse_merge(m, s, mo, so);
    mo = dppf<0x4E>(m); so = dppf<0x4E>(s);
    lse_merge(m, s, mo, so);
}
// 8/16-lane butterflies for the loss phase (R4-proven)
template<int T>
__device__ __forceinline__ float bfly_max(float x) {
    x = fmaxf(x, dppf<0xB1>(x));
    x = fmaxf(x, dppf<0x4E>(x));
    x = fmaxf(x, dppf<0x141>(x));
    if (T == 16) x = fmaxf(x, dppf<0x140>(x));
    return x;
}
template<int T>
__device__ __forceinline__ float bfly_add(float x) {
    x += dppf<0xB1>(x);
    x += dppf<0x4E>(x);
    x += dppf<0x141>(x);
    if (T == 16) x += dppf<0x140>(x);
    return x;
}
// two-pass LSE used by the loss phase (R4-proven)
template<int T, int NUMAX>
__device__ __forceinline__ void load_terms(float* v, int sub, int nterm,
                                           const float* p1, const float* p2, float& mloc) {
    p1 += sub; p2 += sub;
#pragma unroll
    for (int kk = 0; kk < NUMAX; kk += 2) {
        if (kk * T >= nterm) break;
        const int o0 = kk * T, o1 = o0 + T;
        float a0 = p1[o0] + p2[o0];
        float a1 = p1[o1] + p2[o1];
        a0 = (sub + o0 < nterm) ? a0 : -FLT_MAX;
        a1 = (sub + o1 < nterm) ? a1 : -FLT_MAX;
        v[kk] = a0; v[kk + 1] = a1;
        mloc = fmaxf(mloc, fmaxf(a0, a1));
    }
}
template<int T, int NUMAX>
__device__ __forceinline__ void sum_exp(const float* v, int nterm, float M, float& s) {
#pragma unroll
    for (int kk = 0; kk < NUMAX; kk += 2) {
        if (kk * T >= nterm) break;
        s += __expf(v[kk] - M) + __expf(v[kk + 1] - M);
    }
}

// ================= fused kernel: blocks [0,NB) = per-batch DP; [NB,NB+NBCE) = BCE =================
__global__ __launch_bounds__(NT, 1) void tree_dp_kernel(
    const float* __restrict__ logits,
    const int*   __restrict__ spans_ind,
    const void*  __restrict__ maskspan,
    const float* __restrict__ ph, const float* __restrict__ pt,
    const int* __restrict__ ph_ind, const int* __restrict__ pt_ind,
    const void* __restrict__ maskarc,
    double*      __restrict__ ws)
{
    const int tid = threadIdx.x;

    // ---------------- BCE blocks ----------------
    if (blockIdx.x >= NB) {
        const int mode = mask_mode(maskarc);
        const int tot = NB * L * L;
        double sph = 0.0, spt = 0.0, cnt = 0.0;
        for (int idx = (blockIdx.x - NB) * NT + tid; idx < tot; idx += NBCE * NT) {
            if (mask_at(maskarc, mode, idx)) {
                float x = ph[idx]; float y = (float)ph_ind[idx];
                sph += (double)(fmaxf(x, 0.0f) - x * y + log1pf(__expf(-fabsf(x))));
                x = pt[idx]; y = (float)pt_ind[idx];
                spt += (double)(fmaxf(x, 0.0f) - x * y + log1pf(__expf(-fabsf(x))));
                cnt += 1.0;
            }
        }
        for (int off = 32; off > 0; off >>= 1) {
            sph += __shfl_down(sph, off);
            spt += __shfl_down(spt, off);
            cnt += __shfl_down(cnt, off);
        }
        if ((tid & 63) == 0) {
            atomicAdd(&ws[2], sph); atomicAdd(&ws[3], spt); atomicAdd(&ws[4], cnt);
        }
        return;
    }

    // ---------------- DP blocks ----------------
    __shared__ float Am[L * R + PAD];   // mirror-square alpha (init sc)
    __shared__ float Gm[L * R + PAD];   // mirror-square gamma (init sc)
    __shared__ float2 EB[MAXD * 256];   // external LSE partials (m, s) per cell

    const int b = blockIdx.x;
    const int mbase = b * L * L;
    const int mode = mask_mode(maskspan);

    int pred = (tid < L) && mask_at(maskspan, mode, mbase + tid);
    const int n = __syncthreads_count(pred);
    const int D = (n + 15) >> 4;        // tile-diagonal count

    const float* lg = logits + (size_t)b * L * L * 2;

    // ---- init: sc into both mirror halves ----
    for (int e = tid; e < L * L; e += NT) {
        int i = e >> 7, j = e & (L - 1);
        if (i <= j && j < n) {
            const float* p = lg + (size_t)e * 2;
            float v = lse2(p[0], p[1]);
            Am[i * R + j] = v; Am[j * R + i] = v;
            Gm[i * R + j] = v; Gm[j * R + i] = v;
        }
    }
    __syncthreads();

    const int wave = tid >> 6, lane = tid & 63;
    const int cid4 = lane >> 2, sub4 = lane & 3;

    // ============ INSIDE pass ============
    // d = 0: diagonal tiles, one wave each, wave-synchronous
    if (wave < D) {
        const int bI = wave << 4;
        for (int lw = 1; lw < 16; ++lw) {
            int li = cid4, lj = li + lw;
            int i = bI + li, j = bI + lj;
            bool act = (lj < 16) && (j < n);
            float m0 = -FLT_MAX, s0 = 0.f;
            if (act) {
                const float* pL = Am + i * R + i;        // A[i, i+t]
                const float* pR = Am + j * R + i + 1;    // A[i+1+t, j] (mirror)
                for (int t = sub4; t < lw; t += 4)
                    lse_acc(pL[t] + pR[t], m0, s0);
            }
            bfly4_lse(m0, s0);
            if (act && sub4 == 0) {
                float v = Am[i * R + j] + m0 + __logf(s0);   // slot holds sc
                Am[i * R + j] = v; Am[j * R + i] = v;
            }
        }
    }
    __syncthreads();

    // d >= 1
    for (int d = 1; d < D; ++d) {
        const int TD = D - d;
        // ---- phase E: external partials, 1 thread/cell ----
        for (int cidx = tid; cidx < (TD << 8); cidx += NT) {
            int It = cidx >> 8, c = cidx & 255;
            int li = c >> 4, lj = c & 15;
            int i = (It << 4) + li, j = ((It + d) << 4) + lj;
            float m0 = -FLT_MAX, s0 = 0.f, m1 = -FLT_MAX, s1 = 0.f;
            if (j < n) {
                int mlo = (It << 4) + 15;                // external m in [16I+15, 16J)
                int cnt = (d << 4) - 15;
                const float* p1 = Am + i * R + mlo;      // A[i, m]
                const float* p2 = Am + j * R + mlo + 1;  // A[m+1, j] (mirror)
                int t = 0;
                for (; t + 1 < cnt; t += 2) {
                    lse_acc(p1[t] + p2[t], m0, s0);
                    lse_acc(p1[t + 1] + p2[t + 1], m1, s1);
                }
                if (t < cnt) lse_acc(p1[t] + p2[t], m0, s0);
                lse_merge(m0, s0, m1, s1);
            }
            EB[cidx] = make_float2(m0, s0);
        }
        __syncthreads();
        // ---- phase I: one wave per tile, 31 wave-synchronous local steps ----
        if (wave < TD) {
            const int bI = wave << 4, bJ = (wave + d) << 4;
            const int ebase = wave << 8;
            for (int step = 0; step < 31; ++step) {
                int delta = step - 15;
                int li = (delta >= 0) ? cid4 : (cid4 - delta);
                int lj = li + delta;
                int i = bI + li, j = bJ + lj;
                bool act = (li < 16) && (lj < 16) && (j < n);
                float m0 = -FLT_MAX, s0 = 0.f, m1 = -FLT_MAX, s1 = 0.f;
                if (act) {
                    const float* rI = Am + i * R;
                    const float* rJ = Am + j * R;
                    int nL = lj, nR = 15 - li;
                    // group L: A[i,16J+t] (in-tile) + A[16J+1+t, j] (tile (J,J), old)
                    for (int t = sub4; t < nL; t += 4)
                        lse_acc(rI[bJ + t] + rJ[bJ + 1 + t], m0, s0);
                    // group R: A[i,16I+li+t] (tile (I,I), old) + A[16I+li+1+t, j] (in-tile)
                    for (int t = sub4; t < nR; t += 4)
                        lse_acc(rI[bI + li + t] + rJ[bI + li + 1 + t], m1, s1);
                    lse_merge(m0, s0, m1, s1);
                }
                bfly4_lse(m0, s0);
                if (act && sub4 == 0) {
                    float2 e = EB[ebase + (li << 4) + lj];
                    lse_merge(m0, s0, e.x, e.y);
                    float v = Am[i * R + j] + m0 + __logf(s0);
                    Am[i * R + j] = v; Am[j * R + i] = v;
                }
            }
        }
        __syncthreads();
    }

    const float logZ = Am[n - 1];   // alpha[0, n-1]

    // ============ OUTSIDE pass (d descending) ============
    for (int d = D - 1; d >= 0; --d) {
        const int TD = D - d;
        // ---- phase E ----
        for (int cidx = tid; cidx < (TD << 8); cidx += NT) {
            int It = cidx >> 8, c = cidx & 255;
            int li = c >> 4, lj = c & 15;
            int I = It, J = It + d;
            int i = (I << 4) + li, j = (J << 4) + lj;
            float m0 = -FLT_MAX, s0 = 0.f, m1 = -FLT_MAX, s1 = 0.f;
            if (j < n) {
                int k0 = (J + 1) << 4;
                int nEA = n - k0; if (nEA < 0) nEA = 0;    // group A ext: k in [16(J+1), n)
                int t = 0;
                for (; t + 1 < nEA; t += 2) {
                    lse_acc(Gm[i * R + k0 + t] + Am[(j + 1) * R + k0 + t], m0, s0);
                    lse_acc(Gm[i * R + k0 + t + 1] + Am[(j + 1) * R + k0 + t + 1], m1, s1);
                }
                if (t < nEA) lse_acc(Gm[i * R + k0 + t] + Am[(j + 1) * R + k0 + t], m0, s0);
                int nEB_ = I << 4;                          // group B ext: k in [0, 16I)
                t = 0;
                for (; t + 1 < nEB_; t += 2) {
                    lse_acc(Gm[j * R + t] + Am[(i - 1) * R + t], m0, s0);
                    lse_acc(Gm[j * R + t + 1] + Am[(i - 1) * R + t + 1], m1, s1);
                }
                if (t < nEB_) lse_acc(Gm[j * R + t] + Am[(i - 1) * R + t], m0, s0);
                lse_merge(m0, s0, m1, s1);
            }
            EB[cidx] = make_float2(m0, s0);
        }
        __syncthreads();
        // ---- phase I: descending local diagonals ----
        if (wave < TD) {
            const int bI = wave << 4, bJ = (wave + d) << 4;
            const int ebase = wave << 8;
            const int stepLo = (d == 0) ? 16 : 0;   // d=0: only delta 15..1
            for (int step = 30; step >= stepLo; --step) {
                int delta = step - 15;
                int li = (delta >= 0) ? cid4 : (cid4 - delta);
                int lj = li + delta;
                int i = bI + li, j = bJ + lj;
                bool act = (li < 16) && (lj < 16) && (j < n);
                float m0 = -FLT_MAX, s0 = 0.f, m1 = -FLT_MAX, s1 = 0.f;
                if (act) {
                    int nA = 15 - lj; { int lim = n - 1 - j; if (nA > lim) nA = lim; }
                    int nB = li;
                    // group A: G[i, j+1+t] (in-tile) + A[j+1, j+1+t] (tile (J,J), old)
                    for (int t = sub4; t < nA; t += 4)
                        lse_acc(Gm[i * R + j + 1 + t] + Am[(j + 1) * R + j + 1 + t], m0, s0);
                    // group B: G[16I+t, j] (in-tile, mirror) + A[16I+t, i-1] (tile (I,I), old)
                    for (int t = sub4; t < nB; t += 4)
                        lse_acc(Gm[j * R + bI + t] + Am[(i - 1) * R + bI + t], m1, s1);
                    lse_merge(m0, s0, m1, s1);
                }
                bfly4_lse(m0, s0);
                if (act && sub4 == 0) {
                    float2 e = EB[ebase + (li << 4) + lj];
                    lse_merge(m0, s0, e.x, e.y);
                    if (s0 > 0.f) {                      // empty-LSE corner keeps sc
                        float v = Gm[i * R + j] + m0 + __logf(s0);
                        Gm[i * R + j] = v; Gm[j * R + i] = v;
                    }
                }
            }
        }
        __syncthreads();
    }

    // ============ loss phase (R4-proven) ============
    const int* si = spans_ind + mbase;
    double local = 0.0;
    {
        int cell = tid >> 3, sub = tid & 7;       // T=8, nt = n-1 <= 127 -> NUMAX 16
        if (cell < n) {
            int i = cell;
            int nt1 = n - 1 - i;
            float v1[16], v2[16]; float mloc = -FLT_MAX;
            load_terms<8, 16>(v1, sub, nt1, &Gm[i * R + i + 1], &Am[(i + 1) * R + i + 1], mloc);
            load_terms<8, 16>(v2, sub, i,   &Gm[i * R],         &Am[(i - 1) * R],         mloc);
            float M = bfly_max<8>(mloc);
            float s = 0.0f;
            sum_exp<8, 16>(v1, nt1, M, s);
            sum_exp<8, 16>(v2, i,   M, s);
            float S = bfly_add<8>(s);
            if (sub == 0) {
                float beta_ii = M + __logf(S);
                const float* p = lg + ((size_t)i * L + i) * 2;
                int ind = si[i * L + i];
                float lc = (ind == 2) ? p[1] : p[0];
                float logm = beta_ii - logZ + lc;     // alpha_ii == sc_ii cancels
                local += (double)fmaxf(logm, LOGMIN);
            }
        }
    }
    for (int e = tid; e < L * L; e += NT) {
        int i = e >> 7, j = e & (L - 1);
        if (i < j && j < n) {
            const float* p = lg + (size_t)e * 2;
            float a = p[0], cc = p[1];
            float sc = lse2(a, cc);
            int ind = si[e];
            float lc = (ind == 2) ? cc : a;
            float logm = Am[i * R + j] + Gm[i * R + j] - logZ + lc - 2.0f * sc;
            local += (double)fmaxf(logm, LOGMIN);
        }
    }
    for (int off = 32; off > 0; off >>= 1)
        local += __shfl_down(local, off);
    if ((tid & 63) == 0) atomicAdd(&ws[0], local);
    if (tid == 0) atomicAdd(&ws[1], (double)n);
}

// ================= finalize =================
__global__ void finalize_kernel(const double* __restrict__ ws, float* __restrict__ out) {
    double loss_spans = -ws[0] / ws[1];
    double bce = (ws[2] + ws[3]) / ws[4];
    out[0] = (float)(0.5 * loss_spans + 0.5 * bce);
}

extern "C" void kernel_launch(void* const* d_in, const int* in_sizes, int n_in,
                              void* d_out, int out_size, void* d_ws, size_t ws_size,
                              hipStream_t stream) {
    (void)in_sizes; (void)n_in; (void)out_size; (void)ws_size;
    const float* span_logits = (const float*)d_in[0];
    const float* ph          = (const float*)d_in[1];
    const float* pt          = (const float*)d_in[2];
    /* d_in[3] = ph_arc: unused by reference */
    const int*   spans_ind   = (const int*)d_in[4];
    const int*   ph_ind      = (const int*)d_in[5];
    const int*   pt_ind      = (const int*)d_in[6];
    const void*  maskspan    = d_in[7];
    const void*  maskarc     = d_in[8];
    double* ws = (double*)d_ws;
    float* out = (float*)d_out;

    hipMemsetAsync(d_ws, 0, 5 * sizeof(double), stream);
    hipLaunchKernelGGL(tree_dp_kernel, dim3(NB + NBCE), dim3(NT), 0, stream,
                       span_logits, spans_ind, maskspan,
                       ph, pt, ph_ind, pt_ind, maskarc, ws);
    hipLaunchKernelGGL(finalize_kernel, dim3(1), dim3(1), 0, stream, ws, out);
}

// Round 6
// 364.227 us; speedup vs baseline: 1.5153x; 1.5153x over previous
//
#include <hip/hip_runtime.h>
#include <hip/hip_bf16.h>
#include <float.h>

#define NB 32
#define NBCE 32
#define L 128
#define NT 1024
#define R 132                      /* row stride of mirror-square */
#define PAD 40
#define LOGMIN -87.49823f          /* ln(1e-38) */

// ---- mask dtype runtime detection (element [0] is guaranteed true: lens >= 64) ----
__device__ __forceinline__ int mask_mode(const void* p) {
    unsigned int v = ((const unsigned int*)p)[0];
    if (v == 1u) return 1;
    if (v == 0x3F800000u) return 2;
    return 0;
}
__device__ __forceinline__ bool mask_at(const void* p, int mode, int idx) {
    if (mode == 1) return ((const int*)p)[idx] != 0;
    if (mode == 2) return ((const float*)p)[idx] != 0.0f;
    return ((const unsigned char*)p)[idx] != 0;
}

__device__ __forceinline__ float lse2(float a, float b) {
    return fmaxf(a, b) + log1pf(__expf(-fabsf(a - b)));
}

// online-LSE fold of one term into (m, s) state
__device__ __forceinline__ void lse_acc(float v, float& m, float& s) {
    float nm = fmaxf(m, v);
    s = s * __expf(m - nm) + __expf(v - nm);
    m = nm;
}

// ---- DPP butterflies over aligned subgroups of 8 or 16 lanes (R4-proven) ----
template<int C>
__device__ __forceinline__ float dppf(float x) {
    return __int_as_float(__builtin_amdgcn_mov_dpp(__float_as_int(x), C, 0xF, 0xF, true));
}
template<int T>
__device__ __forceinline__ float bfly_max(float x) {
    x = fmaxf(x, dppf<0xB1>(x));
    x = fmaxf(x, dppf<0x4E>(x));
    x = fmaxf(x, dppf<0x141>(x));
    if (T == 16) x = fmaxf(x, dppf<0x140>(x));
    return x;
}
template<int T>
__device__ __forceinline__ float bfly_add(float x) {
    x += dppf<0xB1>(x);
    x += dppf<0x4E>(x);
    x += dppf<0x141>(x);
    if (T == 16) x += dppf<0x140>(x);
    return x;
}
// batched two-pass LSE load (R4-proven): contiguous streams, dynamic trip, padded
template<int T, int NUMAX>
__device__ __forceinline__ void load_terms(float* v, int sub, int nterm,
                                           const float* p1, const float* p2, float& mloc) {
    p1 += sub; p2 += sub;
#pragma unroll
    for (int kk = 0; kk < NUMAX; kk += 2) {
        if (kk * T >= nterm) break;
        const int o0 = kk * T, o1 = o0 + T;
        float a0 = p1[o0] + p2[o0];
        float a1 = p1[o1] + p2[o1];
        a0 = (sub + o0 < nterm) ? a0 : -FLT_MAX;
        a1 = (sub + o1 < nterm) ? a1 : -FLT_MAX;
        v[kk] = a0; v[kk + 1] = a1;
        mloc = fmaxf(mloc, fmaxf(a0, a1));
    }
}
template<int T, int NUMAX>
__device__ __forceinline__ void sum_exp(const float* v, int nterm, float M, float& s) {
#pragma unroll
    for (int kk = 0; kk < NUMAX; kk += 2) {
        if (kk * T >= nterm) break;
        s += __expf(v[kk] - M) + __expf(v[kk + 1] - M);
    }
}

// ================= fused kernel: blocks [0,NB) = per-batch DP; [NB,NB+NBCE) = BCE =================
__global__ __launch_bounds__(NT, 1) void tree_dp_kernel(
    const float* __restrict__ logits,
    const int*   __restrict__ spans_ind,
    const void*  __restrict__ maskspan,
    const float* __restrict__ ph, const float* __restrict__ pt,
    const int* __restrict__ ph_ind, const int* __restrict__ pt_ind,
    const void* __restrict__ maskarc,
    double*      __restrict__ ws)
{
    const int tid = threadIdx.x;

    // ---------------- BCE blocks ----------------
    if (blockIdx.x >= NB) {
        const int mode = mask_mode(maskarc);
        const int tot = NB * L * L;
        double sph = 0.0, spt = 0.0, cnt = 0.0;
        for (int idx = (blockIdx.x - NB) * NT + tid; idx < tot; idx += NBCE * NT) {
            if (mask_at(maskarc, mode, idx)) {
                float x = ph[idx]; float y = (float)ph_ind[idx];
                sph += (double)(fmaxf(x, 0.0f) - x * y + log1pf(__expf(-fabsf(x))));
                x = pt[idx]; y = (float)pt_ind[idx];
                spt += (double)(fmaxf(x, 0.0f) - x * y + log1pf(__expf(-fabsf(x))));
                cnt += 1.0;
            }
        }
        for (int off = 32; off > 0; off >>= 1) {
            sph += __shfl_down(sph, off);
            spt += __shfl_down(spt, off);
            cnt += __shfl_down(cnt, off);
        }
        if ((tid & 63) == 0) {
            atomicAdd(&ws[2], sph); atomicAdd(&ws[3], spt); atomicAdd(&ws[4], cnt);
        }
        return;
    }

    // ---------------- DP blocks ----------------
    __shared__ float Am[L * R + PAD];   // mirror-square alpha (slots init to sc)
    __shared__ float Gm[L * R + PAD];   // mirror-square gamma (slots init to sc)

    const int b = blockIdx.x;
    const int mbase = b * L * L;
    const int mode = mask_mode(maskspan);

    int pred = (tid < L) && mask_at(maskspan, mode, mbase + tid);
    const int n = __syncthreads_count(pred);

    const float* lg = logits + (size_t)b * L * L * 2;

    // ---- init: sc into both mirror halves ----
    for (int e = tid; e < L * L; e += NT) {
        int i = e >> 7, j = e & (L - 1);
        if (i <= j && j < n) {
            const float* p = lg + (size_t)e * 2;
            float v = lse2(p[0], p[1]);
            Am[i * R + j] = v; Am[j * R + i] = v;
            Gm[i * R + j] = v; Gm[j * R + i] = v;
        }
    }
    __syncthreads();

    // ---- inside w = 1: single-term cells, one thread per cell ----
    if (tid < n - 1) {
        int i = tid, j = i + 1;
        float val = Am[i * R + j] + Am[i * R + i] + Am[j * R + j];
        Am[i * R + j] = val; Am[j * R + i] = val;
    }
    // no barrier: w=2's in-loop barrier publishes these writes

    // ---- inside w = 2..n-1, software-pipelined ----
    // bulk: terms m in [i+1, j-2] (both factors width <= w-2, already published)
    // fresh: m=i -> A[i,i]+A[i+1,j]; m=j-1 -> A[i,j-1]+A[j,j]   (width w-1)
    for (int w = 2; w < n; ++w) {
        int c = n - w;
        float M = -FLT_MAX, S = 0.0f;
        float pre_sc = 0.f, pre_di = 0.f, pre_dj = 0.f;
        int i = 0, j = 0, sub = 0; bool act = false; bool lead = false;
        int nb = w - 2;
        if (c > 64) {                       // T=8, nb <= 61 -> NUMAX 8
            int cell = tid >> 3; sub = tid & 7;
            act = cell < c;
            if (act) {
                i = cell; j = i + w;
                float v[8]; float mloc = -FLT_MAX;
                load_terms<8, 8>(v, sub, nb, &Am[i * R + i + 1], &Am[j * R + i + 2], mloc);
                M = bfly_max<8>(mloc);
                float s = 0.0f;
                sum_exp<8, 8>(v, nb, M, s);
                S = bfly_add<8>(s);
            }
        } else {                            // T=16, nb <= 125 -> NUMAX 8
            int cell = tid >> 4; sub = tid & 15;
            act = cell < c;
            if (act) {
                i = cell; j = i + w;
                float v[8]; float mloc = -FLT_MAX;
                load_terms<16, 8>(v, sub, nb, &Am[i * R + i + 1], &Am[j * R + i + 2], mloc);
                M = bfly_max<16>(mloc);
                float s = 0.0f;
                sum_exp<16, 8>(v, nb, M, s);
                S = bfly_add<16>(s);
            }
        }
        lead = act && (sub == 0);
        if (lead) {                          // preload barrier-independent operands
            pre_sc = Am[i * R + j];          // sc slot (unwritten until our own store)
            pre_di = Am[i * R + i];          // diag, init-constant
            pre_dj = Am[j * R + j];
        }
        __syncthreads();                     // publishes width w-1
        if (lead) {
            float f1 = pre_di + Am[j * R + i + 1];   // m = i
            float f2 = Am[i * R + j - 1] + pre_dj;   // m = j-1
            lse_acc(f1, M, S);
            lse_acc(f2, M, S);
            float val = pre_sc + M + __logf(S);
            Am[i * R + j] = val; Am[j * R + i] = val;
        }
    }
    __syncthreads();

    const float logZ = Am[n - 1];   // alpha[0, n-1]

    // ---- outside w = n-2..1, software-pipelined ----
    // bulk: group A k in [j+2, n-1]: G[i,k]+A[j+1,k]; group B k in [0, i-2]: G[k,j]+A[k,i-1]
    // fresh (gamma-width w+1): k=j+1 -> G[i,j+1]+A[j+1,j+1]; k=i-1 -> G[i-1,j]+A[i-1,i-1]
    for (int w = n - 2; w >= 1; --w) {
        int c = n - w;
        float M = -FLT_MAX, S = 0.0f;
        float pre_sc = 0.f, pre_aj = 0.f, pre_ai = 0.f;
        int i = 0, j = 0, sub = 0; bool act = false; bool lead = false;
        if (c > 64) {                       // T=8, each stream <= 126 -> NUMAX 16
            int cell = tid >> 3; sub = tid & 7;
            act = cell < c;
            if (act) {
                i = cell; j = i + w;
                int nA = n - j - 2; if (nA < 0) nA = 0;
                int nB = i - 1;     if (nB < 0) nB = 0;
                float v1[16], v2[16]; float mloc = -FLT_MAX;
                load_terms<8, 16>(v1, sub, nA, &Gm[i * R + j + 2], &Am[(j + 1) * R + j + 2], mloc);
                load_terms<8, 16>(v2, sub, nB, &Gm[j * R],         &Am[(i - 1) * R],         mloc);
                M = bfly_max<8>(mloc);
                float s = 0.0f;
                sum_exp<8, 16>(v1, nA, M, s);
                sum_exp<8, 16>(v2, nB, M, s);
                S = bfly_add<8>(s);
            }
        } else {                            // T=16, each stream <= 62 -> NUMAX 4
            int cell = tid >> 4; sub = tid & 15;
            act = cell < c;
            if (act) {
                i = cell; j = i + w;
                int nA = n - j - 2; if (nA < 0) nA = 0;
                int nB = i - 1;     if (nB < 0) nB = 0;
                float v1[4], v2[4]; float mloc = -FLT_MAX;
                load_terms<16, 4>(v1, sub, nA, &Gm[i * R + j + 2], &Am[(j + 1) * R + j + 2], mloc);
                load_terms<16, 4>(v2, sub, nB, &Gm[j * R],         &Am[(i - 1) * R],         mloc);
                M = bfly_max<16>(mloc);
                float s = 0.0f;
                sum_exp<16, 4>(v1, nA, M, s);
                sum_exp<16, 4>(v2, nB, M, s);
                S = bfly_add<16>(s);
            }
        }
        lead = act && (sub == 0);
        if (lead) {
            pre_sc = Gm[i * R + j];
            pre_aj = (j < n - 1) ? Am[(j + 1) * R + j + 1] : 0.f;   // diag alpha, constant
            pre_ai = (i > 0)     ? Am[(i - 1) * R + i - 1] : 0.f;
        }
        __syncthreads();                     // publishes gamma width w+1
        if (lead) {
            if (j < n - 1) lse_acc(Gm[i * R + j + 1] + pre_aj, M, S);
            if (i > 0)     lse_acc(Gm[(i - 1) * R + j] + pre_ai, M, S);
            float val = pre_sc + M + __logf(S);
            Gm[i * R + j] = val; Gm[j * R + i] = val;
        }
    }
    __syncthreads();

    // ============ loss phase (R4-proven) ============
    const int* si = spans_ind + mbase;
    double local = 0.0;
    {
        int cell = tid >> 3, sub = tid & 7;       // T=8, nt <= 127 -> NUMAX 16
        if (cell < n) {
            int i = cell;
            int nt1 = n - 1 - i;
            float v1[16], v2[16]; float mloc = -FLT_MAX;
            load_terms<8, 16>(v1, sub, nt1, &Gm[i * R + i + 1], &Am[(i + 1) * R + i + 1], mloc);
            load_terms<8, 16>(v2, sub, i,   &Gm[i * R],         &Am[(i - 1) * R],         mloc);
            float M = bfly_max<8>(mloc);
            float s = 0.0f;
            sum_exp<8, 16>(v1, nt1, M, s);
            sum_exp<8, 16>(v2, i,   M, s);
            float S = bfly_add<8>(s);
            if (sub == 0) {
                float beta_ii = M + __logf(S);
                const float* p = lg + ((size_t)i * L + i) * 2;
                int ind = si[i * L + i];
                float lc = (ind == 2) ? p[1] : p[0];
                float logm = beta_ii - logZ + lc;     // alpha_ii == sc_ii cancels
                local += (double)fmaxf(logm, LOGMIN);
            }
        }
    }
    for (int e = tid; e < L * L; e += NT) {
        int i = e >> 7, j = e & (L - 1);
        if (i < j && j < n) {
            const float* p = lg + (size_t)e * 2;
            float a = p[0], cc = p[1];
            float sc = lse2(a, cc);
            int ind = si[e];
            float lc = (ind == 2) ? cc : a;
            float logm = Am[i * R + j] + Gm[i * R + j] - logZ + lc - 2.0f * sc;
            local += (double)fmaxf(logm, LOGMIN);
        }
    }
    for (int off = 32; off > 0; off >>= 1)
        local += __shfl_down(local, off);
    if ((tid & 63) == 0) atomicAdd(&ws[0], local);
    if (tid == 0) atomicAdd(&ws[1], (double)n);
}

// ================= finalize =================
__global__ void finalize_kernel(const double* __restrict__ ws, float* __restrict__ out) {
    double loss_spans = -ws[0] / ws[1];
    double bce = (ws[2] + ws[3]) / ws[4];
    out[0] = (float)(0.5 * loss_spans + 0.5 * bce);
}

extern "C" void kernel_launch(void* const* d_in, const int* in_sizes, int n_in,
                              void* d_out, int out_size, void* d_ws, size_t ws_size,
                              hipStream_t stream) {
    (void)in_sizes; (void)n_in; (void)out_size; (void)ws_size;
    const float* span_logits = (const float*)d_in[0];
    const float* ph          = (const float*)d_in[1];
    const float* pt          = (const float*)d_in[2];
    /* d_in[3] = ph_arc: unused by reference */
    const int*   spans_ind   = (const int*)d_in[4];
    const int*   ph_ind      = (const int*)d_in[5];
    const int*   pt_ind      = (const int*)d_in[6];
    const void*  maskspan    = d_in[7];
    const void*  maskarc     = d_in[8];
    double* ws = (double*)d_ws;
    float* out = (float*)d_out;

    hipMemsetAsync(d_ws, 0, 5 * sizeof(double), stream);
    hipLaunchKernelGGL(tree_dp_kernel, dim3(NB + NBCE), dim3(NT), 0, stream,
                       span_logits, spans_ind, maskspan,
                       ph, pt, ph_ind, pt_ind, maskarc, ws);
    hipLaunchKernelGGL(finalize_kernel, dim3(1), dim3(1), 0, stream, ws, out);
}